// Round 9
// baseline (51.722 us; speedup 1.0000x reference)
//
#include <hip/hip_runtime.h>
#include <math.h>

#define NQ    12
#define NST   4096
#define NBATCH 2048
#define DIM   64
#define NCLS  4
#define TPB   256
#define APT   16

typedef float v2f __attribute__((ext_vector_type(2)));   // (re, im)

// Ring permutation (round-1 verified): new[d] = old[P(d)]; GF(2)-linear.
constexpr unsigned Pm(unsigned j) { return j ^ (j >> 1) ^ ((j & 1u) * 0xC00u); }
// Storage map: a[0:3] = j[0:3]^j[4:7], a[4:11] = j[4:11]. Involution, bijective.
// All six access patterns (A/B phase x maps S, S∘P, S∘P²) verified rank-4 over
// lane bits -> bank-conflict-free b64 (round 8, conflicts 3.9M ≈ noise).
constexpr unsigned Sm(unsigned j) { return j ^ ((j >> 4) & 0xFu); }

// A-phase lane->logical: l0..l5,w0,w1 -> bits 4..11 ; k -> bits 0..3
__device__ __forceinline__ unsigned alphaA(unsigned t) { return t << 4; }
// B-phase: l2..l5 -> bits 0..3, w0,w1 -> bits 4,5, l0,l1 -> bits 6,7 ; k -> bits 8..11
__device__ __forceinline__ unsigned alphaB(unsigned t) {
    unsigned lane = t & 63u, w = t >> 6;
    return ((lane >> 2) & 0xFu) | (w << 4) | ((lane & 3u) << 6);
}

__device__ __forceinline__ v2f cmul(v2f x, v2f y) {
    v2f r; r.x = x.x*y.x - x.y*y.y; r.y = x.x*y.y + x.y*y.x; return r;
}

// packed f32 ops (VOP3P)
__device__ __forceinline__ v2f pk_mul(v2f a, v2f b) {
    v2f d; asm("v_pk_mul_f32 %0, %1, %2" : "=v"(d) : "v"(a), "v"(b)); return d;
}
__device__ __forceinline__ v2f pk_fma(v2f a, v2f b, v2f c) {
    v2f d; asm("v_pk_fma_f32 %0, %1, %2, %3" : "=v"(d) : "v"(a), "v"(b), "v"(c)); return d;
}

// lane exchange via quad_perm DPP only (XB in {1,2})
template<int XB>
__device__ __forceinline__ float lx(float v) {
    int i = __float_as_int(v);
    if constexpr (XB == 1)
        return __int_as_float(__builtin_amdgcn_update_dpp(i, i, 0xB1, 0xF, 0xF, true)); // [1,0,3,2]
    else
        return __int_as_float(__builtin_amdgcn_update_dpp(i, i, 0x4E, 0xF, 0xF, true)); // [2,3,0,1]
}

// real RY on intra-register bit P (0..3)
template<int P>
__device__ __forceinline__ void intra_g(v2f (&a)[APT], float c, float s) {
    const v2f cc = {c, c}, ss = {s, s}, ns = {-s, -s};
    #pragma unroll
    for (int k = 0; k < APT; ++k) {
        if (!(k & (1 << P))) {
            const int k1 = k | (1 << P);
            v2f x0 = a[k], x1 = a[k1];
            a[k]  = pk_fma(ns, x1, pk_mul(cc, x0));   // c*x0 - s*x1
            a[k1] = pk_fma(cc, x1, pk_mul(ss, x0));   // s*x0 + c*x1
        }
    }
}

// real RY on lane bit XB (quad_perm exchange)
template<int XB>
__device__ __forceinline__ void lane_g(v2f (&a)[APT], float c, float s, int lane) {
    const float br = (lane & XB) ? s : -s;
    const v2f cc = {c, c}, bb = {br, br};
    #pragma unroll
    for (int k = 0; k < APT; ++k) {
        v2f o; o.x = lx<XB>(a[k].x); o.y = lx<XB>(a[k].y);
        a[k] = pk_fma(bb, o, pk_mul(cc, a[k]));
    }
}

// A phase: intra bits0-3 = q11,q10,q9,q8 ; lanes l0->bit4 (q7), l1->bit5 (q6)
__device__ __forceinline__ void gates_A(v2f (&a)[APT], const float* __restrict__ cs, int lane) {
    intra_g<0>(a, cs[22], cs[23]);
    intra_g<1>(a, cs[20], cs[21]);
    intra_g<2>(a, cs[18], cs[19]);
    intra_g<3>(a, cs[16], cs[17]);
    lane_g<1>(a, cs[14], cs[15], lane);
    lane_g<2>(a, cs[12], cs[13], lane);
}
// B phase: intra k bits -> logical 8-11 = q3,q2,q1,q0 ; l0->bit6 (q5), l1->bit7 (q4)
__device__ __forceinline__ void gates_B(v2f (&a)[APT], const float* __restrict__ cs, int lane) {
    intra_g<0>(a, cs[6], cs[7]);
    intra_g<1>(a, cs[4], cs[5]);
    intra_g<2>(a, cs[2], cs[3]);
    intra_g<3>(a, cs[0], cs[1]);
    lane_g<1>(a, cs[10], cs[11], lane);
    lane_g<2>(a, cs[8],  cs[9],  lane);
}

// ws layout (floats): [0..71] RY c/s layers1-3 (24/layer, q*2);
// [72..135] kD layers1-2 (16 v2f each); [136..1159] thrD layers1-2 (256 v2f each)
__global__ void vqc_setup(const float* __restrict__ qw, float* __restrict__ gp) {
    const int t = threadIdx.x;
    if (t < 36) {
        int l = t / 12 + 1, q = t % 12;
        float cc, ss; sincosf(0.5f * qw[(l*NQ + q)*2], &ss, &cc);
        gp[(l-1)*24 + q*2 + 0] = cc;
        gp[(l-1)*24 + q*2 + 1] = ss;
    }
    if (t < 32) {                       // kD: logical bit 8+i -> qubit 3-i
        int l = t / 16 + 1, k = t % 16;
        float ang = 0.f;
        #pragma unroll
        for (int i = 0; i < 4; ++i)
            if ((k >> i) & 1) ang += qw[(l*NQ + (3 - i))*2 + 1];
        float s_, c_; sincosf(ang, &s_, &c_);
        gp[72 + (l-1)*32 + k*2 + 0] = c_;
        gp[72 + (l-1)*32 + k*2 + 1] = s_;
    }
    const unsigned j = alphaB((unsigned)t);   // bits 0..7
    #pragma unroll
    for (int l = 1; l <= 2; ++l) {
        float ang = 0.f;
        #pragma unroll
        for (int b = 0; b < 8; ++b)
            if ((j >> b) & 1) ang += qw[(l*NQ + (11 - b))*2 + 1];
        float s_, c_; sincosf(ang, &s_, &c_);
        gp[136 + (l-1)*512 + t*2 + 0] = c_;
        gp[136 + (l-1)*512 + t*2 + 1] = s_;
    }
}

// LDS = exactly 32768 B (160KiB/32768 = 5 blocks/CU, was 4 at 33792).
// xs/g0 alias the buf region (dead before first buf write); zred/zfin alias it
// too (born after last buf read). Two extra barriers enforce the lifetimes.
__global__ __launch_bounds__(TPB, 5) void vqc_kernel(
    const float* __restrict__ x,
    const float* __restrict__ Win,
    const float* __restrict__ bin,
    const float* __restrict__ qw,
    const float* __restrict__ Wout,
    const float* __restrict__ bout,
    const float* __restrict__ gp,
    float* __restrict__ out)
{
    __shared__ __align__(16) char smem[32768];
    v2f*   buf  = (v2f*)smem;
    float* xs   = (float*)smem;          // floats [0,64)   — dead before buf use
    float* g0c  = xs + 64;               // [64,76)
    float* g0r  = xs + 76;               // [76,88)
    float* g0i  = xs + 88;               // [88,100)
    float* zred = xs;                    // [0,40)  — born after buf dead
    float* zfin = xs + 40;               // [40,52)

    const int tid  = threadIdx.x;
    const int lane = tid & 63;
    const int wv   = tid >> 6;
    const int b    = blockIdx.x;

    const unsigned aA = alphaA((unsigned)tid), aB = alphaB((unsigned)tid);
    const unsigned A1 = Sm(aA),         B1 = Sm(aB);
    const unsigned A2 = Sm(Pm(aA)),     B2 = Sm(Pm(aB));
    const unsigned A3 = Sm(Pm(Pm(aA))), B3 = Sm(Pm(Pm(aB)));

    // ---- stage x ----
    if (tid < DIM) xs[tid] = x[b*DIM + tid];
    __syncthreads();

    // ---- encoding matvec (16 lanes/qubit); layer-0 factors (RY+RZ folded) ----
    if (tid < 192) {
        const int q = tid >> 4, r = tid & 15;
        float acc = xs[r] * Win[q*DIM + r]
                  + xs[r+16] * Win[q*DIM + r + 16]
                  + xs[r+32] * Win[q*DIM + r + 32]
                  + xs[r+48] * Win[q*DIM + r + 48];
        acc += __shfl_xor(acc, 8, 16);
        acc += __shfl_xor(acc, 4, 16);
        acc += __shfl_xor(acc, 2, 16);
        acc += __shfl_xor(acc, 1, 16);
        if (r == 0) {
            acc += bin[q];
            float ang = tanhf(acc) * 3.14159265358979323846f;
            float th  = ang + qw[(0*NQ + q)*2 + 0];
            float ph  = qw[(0*NQ + q)*2 + 1];
            float cc, ss; sincosf(0.5f*th, &ss, &cc);
            float pcv, psv; sincosf(ph, &psv, &pcv);
            g0c[q] = cc; g0r[q] = ss*pcv; g0i[q] = ss*psv;
        }
    }
    __syncthreads();

    v2f a[APT];

    // ---- layer 0 + first ring as relabel: a[k] = prod-state at n = nb ^ Pm(k) ----
    {
        const unsigned nb = Pm(aA);
        v2f thrP = (v2f){1.f, 0.f};
        #pragma unroll
        for (int bb = 4; bb <= 9; ++bb) {
            const int q = 11 - bb;
            const bool bit = (nb >> bb) & 1u;
            v2f f; f.x = bit ? g0r[q] : g0c[q]; f.y = bit ? g0i[q] : 0.f;
            thrP = cmul(thrP, f);
        }
        const bool n10 = (nb >> 10) & 1u, n11 = (nb >> 11) & 1u;
        v2f h10a; h10a.x = n10 ? g0r[1] : g0c[1]; h10a.y = n10 ? g0i[1] : 0.f;
        v2f h10b; h10b.x = n10 ? g0c[1] : g0r[1]; h10b.y = n10 ? 0.f : g0i[1];
        v2f h11a; h11a.x = n11 ? g0r[0] : g0c[0]; h11a.y = n11 ? g0i[0] : 0.f;
        v2f h11b; h11b.x = n11 ? g0c[0] : g0r[0]; h11b.y = n11 ? 0.f : g0i[0];
        v2f TT0 = cmul(thrP, cmul(h10a, h11a));   // k even
        v2f TT1 = cmul(thrP, cmul(h10b, h11b));   // k odd: bits 10,11 flipped
        v2f u[4], w[4];
        #pragma unroll
        for (int bb = 0; bb < 4; ++bb) {
            const int q = 11 - bb;
            const bool bit = (nb >> bb) & 1u;
            u[bb].x = bit ? g0r[q] : g0c[q]; u[bb].y = bit ? g0i[q] : 0.f;
            w[bb].x = bit ? g0c[q] : g0r[q]; w[bb].y = bit ? 0.f : g0i[q];
        }
        v2f P01[4], P23[4];
        #pragma unroll
        for (int c = 0; c < 4; ++c) {
            P01[c] = cmul((c & 1) ? w[0] : u[0], (c & 2) ? w[1] : u[1]);
            P23[c] = cmul((c & 1) ? w[2] : u[2], (c & 2) ? w[3] : u[3]);
        }
        #pragma unroll
        for (int k = 0; k < APT; ++k) {
            const unsigned kp = (unsigned)k ^ ((unsigned)k >> 1);
            v2f g = cmul(P01[kp & 3], P23[(kp >> 2) & 3]);
            a[k] = cmul((k & 1) ? TT1 : TT0, g);
        }
    }

    const float* cs1 = gp, *cs2 = gp + 24, *cs3 = gp + 48;
    const v2f tD1 = *(const v2f*)(gp + 136 + tid*2);
    const v2f tD2 = *(const v2f*)(gp + 136 + 512 + tid*2);

    // ================= layer 1 (map S) =================
    gates_A(a, cs1, lane);
    __syncthreads();   // g0 region is about to be overwritten by the A-write
    {   // b128 A-write: k offsets = k, pairs adjacent
        float4* f4 = (float4*)buf;
        const int a0 = (int)(A1 & 1u);
        #pragma unroll
        for (int ke = 0; ke < APT; ke += 2) {
            v2f lo = a0 ? a[ke+1] : a[ke];
            v2f hi = a0 ? a[ke]   : a[ke+1];
            f4[(A1 ^ (unsigned)ke) >> 1] = make_float4(lo.x, lo.y, hi.x, hi.y);
        }
    }
    __syncthreads();
    #pragma unroll
    for (int k = 0; k < APT; ++k) a[k] = buf[B1 ^ ((unsigned)k << 8)];
    gates_B(a, cs1, lane);
    #pragma unroll
    for (int k = 0; k < APT; ++k) {   // RZ diagonal layer 1
        v2f kd = *(const v2f*)(gp + 72 + k*2);
        buf[B1 ^ ((unsigned)k << 8)] = cmul(cmul(a[k], tD1), kd);
    }
    __syncthreads();

    // ================= layer 2 (map S∘P) =================
    #pragma unroll
    for (int k = 0; k < APT; ++k) a[k] = buf[A2 ^ Sm(Pm((unsigned)k))];
    gates_A(a, cs2, lane);
    #pragma unroll
    for (int k = 0; k < APT; ++k) buf[A2 ^ Sm(Pm((unsigned)k))] = a[k];
    __syncthreads();
    #pragma unroll
    for (int k = 0; k < APT; ++k) a[k] = buf[B2 ^ Sm(Pm((unsigned)k << 8))];
    gates_B(a, cs2, lane);
    #pragma unroll
    for (int k = 0; k < APT; ++k) {   // RZ diagonal layer 2
        v2f kd = *(const v2f*)(gp + 72 + 32 + k*2);
        buf[B2 ^ Sm(Pm((unsigned)k << 8))] = cmul(cmul(a[k], tD2), kd);
    }
    __syncthreads();

    // ================= layer 3 (map S∘P², RZ dropped, ends in regs) =================
    #pragma unroll
    for (int k = 0; k < APT; ++k) a[k] = buf[A3 ^ Sm(Pm(Pm((unsigned)k)))];
    gates_A(a, cs3, lane);
    #pragma unroll
    for (int k = 0; k < APT; ++k) buf[A3 ^ Sm(Pm(Pm((unsigned)k)))] = a[k];
    __syncthreads();
    #pragma unroll
    for (int k = 0; k < APT; ++k) a[k] = buf[B3 ^ Sm(Pm(Pm((unsigned)k << 8)))];
    gates_B(a, cs3, lane);

    // ---- measurement; final ring via masks mu_p = P^{-T} e_p on m = aB ^ (k<<8).
    // k-masks: p<=8 -> 0xF (WF), p=9 -> 0xE (WE), p=10 -> 0xC (WC), p=11 -> 0x7 (W7)
    __syncthreads();   // all layer-3 B-reads done; buf region becomes zred
    {
        float p[APT];
        #pragma unroll
        for (int k = 0; k < APT; ++k) p[k] = fmaf(a[k].x, a[k].x, a[k].y*a[k].y);
        float A_[8], Bm[8];
        #pragma unroll
        for (int j = 0; j < 8; ++j) { A_[j] = p[2*j] + p[2*j+1]; Bm[j] = p[2*j] - p[2*j+1]; }
        float AA[4], AB[4], BB[4];
        #pragma unroll
        for (int i = 0; i < 4; ++i) {
            AA[i] = A_[2*i] + A_[2*i+1];
            AB[i] = A_[2*i] - A_[2*i+1];
            BB[i] = Bm[2*i] - Bm[2*i+1];
        }
        float WF = BB[0] - BB[1] - BB[2] + BB[3];
        float W7 = BB[0] - BB[1] + BB[2] - BB[3];
        float WE = AB[0] - AB[1] - AB[2] + AB[3];
        float WC = AA[0] - AA[1] - AA[2] + AA[3];
        #pragma unroll
        for (int t = 0; t < 6; ++t) {
            float oF = __shfl_xor(WF, 1 << t, 64);
            float o7 = __shfl_xor(W7, 1 << t, 64);
            float oE = __shfl_xor(WE, 1 << t, 64);
            float oC = __shfl_xor(WC, 1 << t, 64);
            const bool hi = (lane >> t) & 1;
            WF = hi ? (oF - WF) : (WF + oF);
            W7 = hi ? (o7 - W7) : (W7 + o7);
            WE = hi ? (oE - WE) : (WE + oE);
            WC = hi ? (oC - WC) : (WC + oC);
        }
        // lane masks (from nu_p mapped through alphaB): p0..8 -> 63,59,51,35,3,3,3,2,0
        if      (lane == 63) { zred[wv*10 + 0] = WF; zred[wv*10 + 9] = W7; }
        else if (lane == 59) { zred[wv*10 + 1] = WF; }
        else if (lane == 51) { zred[wv*10 + 2] = WF; }
        else if (lane == 35) { zred[wv*10 + 3] = WF; }
        else if (lane ==  3) { zred[wv*10 + 4] = WF; }
        else if (lane ==  2) { zred[wv*10 + 5] = WF; }
        else if (lane ==  0) { zred[wv*10 + 6] = WF; zred[wv*10 + 7] = WE; zred[wv*10 + 8] = WC; }
    }
    __syncthreads();
    if (tid < NQ) {     // q = tid ; p = 11-q ; wave-sign masks over (w0,w1)
        const int slotT[12] = {9,8,7,6,5,4,4,4,3,2,1,0};
        const int wmT[12]   = {3,0,0,0,0,0,2,3,3,3,3,3};
        const int sl = slotT[tid], wm = wmT[tid];
        float acc = 0.f;
        #pragma unroll
        for (int W = 0; W < 4; ++W) {
            float v = zred[W*10 + sl];
            acc += (__popc(W & wm) & 1) ? -v : v;
        }
        zfin[tid] = acc;
    }
    __syncthreads();

    if (tid < NCLS) {
        float acc = bout[tid];
        #pragma unroll
        for (int q = 0; q < NQ; ++q) acc += zfin[q] * Wout[tid*NQ + q];
        out[b*NCLS + tid] = acc;
    }
}

extern "C" void kernel_launch(void* const* d_in, const int* in_sizes, int n_in,
                              void* d_out, int out_size, void* d_ws, size_t ws_size,
                              hipStream_t stream) {
    const float* x    = (const float*)d_in[0];
    const float* Win  = (const float*)d_in[1];
    const float* bin  = (const float*)d_in[2];
    const float* qw   = (const float*)d_in[3];
    const float* Wout = (const float*)d_in[4];
    const float* bout = (const float*)d_in[5];
    float* gp  = (float*)d_ws;       // 1160 floats
    float* out = (float*)d_out;
    hipLaunchKernelGGL(vqc_setup, dim3(1), dim3(TPB), 0, stream, qw, gp);
    hipLaunchKernelGGL(vqc_kernel, dim3(NBATCH), dim3(TPB), 0, stream,
                       x, Win, bin, qw, Wout, bout, gp, out);
}